// Round 1
// baseline (504.390 us; speedup 1.0000x reference)
//
#include <hip/hip_runtime.h>

#define DIM 64
#define HID 256   // 4*dim

// ---------------------------------------------------------------------------
// Kernel 1: per-node precompute.
//   tab[i] = [ x[i] @ W1[0:64,:] + b1  |  x[i] @ W1[64:128,:] ]   (512 floats)
// Each thread j owns output unit j (j in [0,256)) and caches both W1 columns
// (64+64 floats) in registers; x-row reads are wave-uniform -> scalar loads.
// ---------------------------------------------------------------------------
__global__ __launch_bounds__(256) void node_precompute(
    const float* __restrict__ x, const float* __restrict__ W1,
    const float* __restrict__ b1, float* __restrict__ tab, int n)
{
    const int j = threadIdx.x;
    float colA[DIM], colB[DIM];
#pragma unroll
    for (int k = 0; k < DIM; ++k) {
        colA[k] = W1[k * HID + j];
        colB[k] = W1[(k + DIM) * HID + j];
    }
    const float bj = b1[j];
    for (int i = blockIdx.x; i < n; i += gridDim.x) {
        const float* __restrict__ xr = x + (size_t)i * DIM;
        float accA = bj, accB = 0.0f;
#pragma unroll
        for (int k = 0; k < DIM; ++k) {
            const float xv = xr[k];        // wave-uniform address -> s_load
            accA = fmaf(xv, colA[k], accA);
            accB = fmaf(xv, colB[k], accB);
        }
        float* __restrict__ trow = tab + (size_t)i * (2 * HID);
        trow[j]       = accA;
        trow[HID + j] = accB;
    }
}

// ---------------------------------------------------------------------------
// Kernel 2: per-edge MLP tail. One wave (64 lanes) per edge; lane l holds
// units [4l, 4l+4) as float4.  out[e] = 0.5 * sum_j( relu(A[s]+B[d])_j
//                                                 + relu(A[d]+B[s])_j )*W2_j + b2
// ---------------------------------------------------------------------------
__global__ __launch_bounds__(256) void edge_mlp(
    const int* __restrict__ ei, const float* __restrict__ tab,
    const float* __restrict__ W2, const float* __restrict__ b2,
    float* __restrict__ out, int ne)
{
    const int lane = threadIdx.x & 63;
    const int wid  = blockIdx.x * (blockDim.x >> 6) + (threadIdx.x >> 6);
    const int nw   = gridDim.x * (blockDim.x >> 6);
    const float4 w = *(const float4*)(W2 + lane * 4);
    const float bias = b2[0];

    for (int e = wid; e < ne; e += nw) {
        const int eu = __builtin_amdgcn_readfirstlane(e);  // force wave-uniform
        const int s = ei[eu];        // scalar loads (uniform index)
        const int d = ei[ne + eu];
        const float* __restrict__ rs = tab + (size_t)s * (2 * HID);
        const float* __restrict__ rd = tab + (size_t)d * (2 * HID);
        const float4 as = *(const float4*)(rs + lane * 4);         // A[s]
        const float4 bs = *(const float4*)(rs + HID + lane * 4);   // B[s]
        const float4 ad = *(const float4*)(rd + lane * 4);         // A[d]
        const float4 bd = *(const float4*)(rd + HID + lane * 4);   // B[d]

        float p = 0.0f;
        p = fmaf(fmaxf(as.x + bd.x, 0.0f), w.x, p);
        p = fmaf(fmaxf(as.y + bd.y, 0.0f), w.y, p);
        p = fmaf(fmaxf(as.z + bd.z, 0.0f), w.z, p);
        p = fmaf(fmaxf(as.w + bd.w, 0.0f), w.w, p);
        p = fmaf(fmaxf(ad.x + bs.x, 0.0f), w.x, p);
        p = fmaf(fmaxf(ad.y + bs.y, 0.0f), w.y, p);
        p = fmaf(fmaxf(ad.z + bs.z, 0.0f), w.z, p);
        p = fmaf(fmaxf(ad.w + bs.w, 0.0f), w.w, p);

#pragma unroll
        for (int off = 32; off > 0; off >>= 1)
            p += __shfl_down(p, off, 64);

        if (lane == 0) out[e] = 0.5f * p + bias;
    }
}

// ---------------------------------------------------------------------------
// Inputs (setup_inputs order):
//  0: x           [N,64]   fp32
//  1: edge_index3 [2,E]    int (harness passes integer inputs as int32)
//  2: edge_attr3  [E,16]   fp32   (unused)
//  3: edge_attr4  [E,16]   fp32   (unused)
//  4: batch       [N]      int    (unused)
//  5: W1          [128,256] fp32
//  6: b1          [256]    fp32
//  7: W2          [256,1]  fp32
//  8: b2          [1]      fp32
// Output: [E] fp32.  Workspace: N*512 fp32 table (102.4 MB).
// ---------------------------------------------------------------------------
extern "C" void kernel_launch(void* const* d_in, const int* in_sizes, int n_in,
                              void* d_out, int out_size, void* d_ws, size_t ws_size,
                              hipStream_t stream) {
    const float* x  = (const float*)d_in[0];
    const int*   ei = (const int*)d_in[1];
    const float* W1 = (const float*)d_in[5];
    const float* b1 = (const float*)d_in[6];
    const float* W2 = (const float*)d_in[7];
    const float* b2 = (const float*)d_in[8];
    float* out = (float*)d_out;

    const int n  = in_sizes[0] / DIM;  // 50000 nodes
    const int ne = in_sizes[1] / 2;    // 500000 edges

    float* tab = (float*)d_ws;         // [n, 512] interleaved A|B rows

    node_precompute<<<2048, 256, 0, stream>>>(x, W1, b1, tab, n);
    edge_mlp<<<4096, 256, 0, stream>>>(ei, tab, W2, b2, out, ne);
}

// Round 2
// 287.605 us; speedup vs baseline: 1.7538x; 1.7538x over previous
//
#include <hip/hip_runtime.h>

#define DIM 64
#define HID 256           // 4*dim
#define ROW 512           // bf16 entries per node row: [A(256)|B(256)]

// float -> bf16 (RNE) packed pair
__device__ __forceinline__ unsigned pk_bf16(float a, float b) {
    unsigned ua = __float_as_uint(a);
    unsigned ub = __float_as_uint(b);
    ua = (ua + 0x7fffu + ((ua >> 16) & 1u)) >> 16;
    ub = (ub + 0x7fffu + ((ub >> 16) & 1u)) & 0xffff0000u;
    return ua | ub;
}
#define BFLO(u) __uint_as_float((u) << 16)
#define BFHI(u) __uint_as_float((u) & 0xffff0000u)

// ---------------------------------------------------------------------------
// Kernel 1: tiled fp32 GEMM  C[n x 512] = X[n x 64] @ [W1top | W1bot][64 x 512]
// (+ b1 on the first 256 cols), stored as bf16 rows of 512.
// Block: 256 threads = (tx 0..31 cols x4, ty 0..7 rows x8). Tile 64r x 128c.
// ---------------------------------------------------------------------------
__global__ __launch_bounds__(256) void node_gemm(
    const float* __restrict__ x, const float* __restrict__ W1,
    const float* __restrict__ b1, unsigned short* __restrict__ tab, int n)
{
    __shared__ float Xs[64][65];    // transposed: Xs[k][row]  (pad 65: no WR conflicts)
    __shared__ float Ws[64][132];   // Ws[k][c]

    const int tid = threadIdx.x;
    const int rb  = (blockIdx.x >> 2) * 64;
    const int cb  = (blockIdx.x & 3) * 128;          // global col base 0..511

    // ---- stage X tile (64 rows x 64 k), transposed ----
    {
        const int r0 = tid >> 4;                     // 0..15
        const int c4 = (tid & 15) * 4;
#pragma unroll
        for (int it = 0; it < 4; ++it) {
            const int r  = r0 + it * 16;
            const int gr = rb + r;
            float4 v = make_float4(0.f, 0.f, 0.f, 0.f);
            if (gr < n) v = *(const float4*)(x + (size_t)gr * DIM + c4);
            Xs[c4 + 0][r] = v.x; Xs[c4 + 1][r] = v.y;
            Xs[c4 + 2][r] = v.z; Xs[c4 + 3][r] = v.w;
        }
    }
    // ---- stage W tile (64 k x 128 c) ----
    {
        const float* __restrict__ wsrc = W1 + ((cb >= 256) ? 64 * HID : 0);
        const int col0 = cb & 255;
        const int c4 = (tid & 31) * 4;               // 0..124
        const int k0 = tid >> 5;                     // 0..7
#pragma unroll
        for (int it = 0; it < 8; ++it) {
            const int k = k0 + it * 8;
            float4 v = *(const float4*)(wsrc + k * HID + col0 + c4);
            Ws[k][c4 + 0] = v.x; Ws[k][c4 + 1] = v.y;
            Ws[k][c4 + 2] = v.z; Ws[k][c4 + 3] = v.w;
        }
    }
    __syncthreads();

    const int tx = tid & 31;    // cols cb + tx*4 .. +4
    const int ty = tid >> 5;    // rows rb + ty*8 .. +8

    float acc[8][4];
    {
        float4 bv = make_float4(0.f, 0.f, 0.f, 0.f);
        if (cb < 256) bv = *(const float4*)(b1 + cb + tx * 4);
#pragma unroll
        for (int rr = 0; rr < 8; ++rr) {
            acc[rr][0] = bv.x; acc[rr][1] = bv.y;
            acc[rr][2] = bv.z; acc[rr][3] = bv.w;
        }
    }

#pragma unroll 4
    for (int k = 0; k < 64; ++k) {
        float xv[8];
#pragma unroll
        for (int rr = 0; rr < 8; ++rr) xv[rr] = Xs[k][ty * 8 + rr];
        const float4 wv = *(const float4*)(&Ws[k][tx * 4]);
#pragma unroll
        for (int rr = 0; rr < 8; ++rr) {
            acc[rr][0] = fmaf(xv[rr], wv.x, acc[rr][0]);
            acc[rr][1] = fmaf(xv[rr], wv.y, acc[rr][1]);
            acc[rr][2] = fmaf(xv[rr], wv.z, acc[rr][2]);
            acc[rr][3] = fmaf(xv[rr], wv.w, acc[rr][3]);
        }
    }

    // ---- store 8 rows x 4 cols as bf16 (uint2 = 4 bf16) ----
#pragma unroll
    for (int rr = 0; rr < 8; ++rr) {
        const int gr = rb + ty * 8 + rr;
        if (gr < n) {
            uint2 o;
            o.x = pk_bf16(acc[rr][0], acc[rr][1]);
            o.y = pk_bf16(acc[rr][2], acc[rr][3]);
            *(uint2*)(tab + (size_t)gr * ROW + cb + tx * 4) = o;
        }
    }
}

// ---------------------------------------------------------------------------
// Kernel 2: per-edge MLP tail. One wave per edge (2 edges/iter).
// Node row = 1 KB contiguous bf16 [A|B]; lane l reads 16 B (8 bf16).
// Lanes <32 hold A-chunks, lanes >=32 hold B-chunks. __shfl_xor(.,32) on the
// d-row swaps halves so every lane computes relu(hs + hd_swapped) . W2chunk:
//   lanes <32  : relu(A[s]+B[d]) . W2   (direction 1)
//   lanes >=32 : relu(B[s]+A[d]) . W2   (direction 2)
// Full 64-lane sum = term1 + term2; out = 0.5*sum + b2.
// ---------------------------------------------------------------------------
__global__ __launch_bounds__(256) void edge_mlp(
    const int* __restrict__ ei, const unsigned short* __restrict__ tab,
    const float* __restrict__ W2, const float* __restrict__ b2,
    float* __restrict__ out, int ne)
{
    const int lane = threadIdx.x & 63;
    const int wid  = blockIdx.x * (blockDim.x >> 6) + (threadIdx.x >> 6);
    const int nw   = gridDim.x * (blockDim.x >> 6);
    const int ub   = 8 * (lane & 31);
    const float4 w0 = *(const float4*)(W2 + ub);
    const float4 w1 = *(const float4*)(W2 + ub + 4);
    const float bias = b2[0];

    for (int e0 = wid * 2; e0 < ne; e0 += nw * 2) {
        const int eu = __builtin_amdgcn_readfirstlane(e0);
        const int sA = ei[eu],     dA = ei[ne + eu];
        const int sB = ei[eu + 1], dB = ei[ne + eu + 1];

        const uint4 hsA = ((const uint4*)(tab + (size_t)sA * ROW))[lane];
        const uint4 hdA = ((const uint4*)(tab + (size_t)dA * ROW))[lane];
        const uint4 hsB = ((const uint4*)(tab + (size_t)sB * ROW))[lane];
        const uint4 hdB = ((const uint4*)(tab + (size_t)dB * ROW))[lane];

        uint4 xA, xB;   // d-rows with A/B halves swapped across the wave
        xA.x = (unsigned)__shfl_xor((int)hdA.x, 32, 64);
        xA.y = (unsigned)__shfl_xor((int)hdA.y, 32, 64);
        xA.z = (unsigned)__shfl_xor((int)hdA.z, 32, 64);
        xA.w = (unsigned)__shfl_xor((int)hdA.w, 32, 64);
        xB.x = (unsigned)__shfl_xor((int)hdB.x, 32, 64);
        xB.y = (unsigned)__shfl_xor((int)hdB.y, 32, 64);
        xB.z = (unsigned)__shfl_xor((int)hdB.z, 32, 64);
        xB.w = (unsigned)__shfl_xor((int)hdB.w, 32, 64);

        float pA = 0.f, pB = 0.f;
        pA = fmaf(fmaxf(BFLO(hsA.x) + BFLO(xA.x), 0.f), w0.x, pA);
        pA = fmaf(fmaxf(BFHI(hsA.x) + BFHI(xA.x), 0.f), w0.y, pA);
        pA = fmaf(fmaxf(BFLO(hsA.y) + BFLO(xA.y), 0.f), w0.z, pA);
        pA = fmaf(fmaxf(BFHI(hsA.y) + BFHI(xA.y), 0.f), w0.w, pA);
        pA = fmaf(fmaxf(BFLO(hsA.z) + BFLO(xA.z), 0.f), w1.x, pA);
        pA = fmaf(fmaxf(BFHI(hsA.z) + BFHI(xA.z), 0.f), w1.y, pA);
        pA = fmaf(fmaxf(BFLO(hsA.w) + BFLO(xA.w), 0.f), w1.z, pA);
        pA = fmaf(fmaxf(BFHI(hsA.w) + BFHI(xA.w), 0.f), w1.w, pA);

        pB = fmaf(fmaxf(BFLO(hsB.x) + BFLO(xB.x), 0.f), w0.x, pB);
        pB = fmaf(fmaxf(BFHI(hsB.x) + BFHI(xB.x), 0.f), w0.y, pB);
        pB = fmaf(fmaxf(BFLO(hsB.y) + BFLO(xB.y), 0.f), w0.z, pB);
        pB = fmaf(fmaxf(BFHI(hsB.y) + BFHI(xB.y), 0.f), w0.w, pB);
        pB = fmaf(fmaxf(BFLO(hsB.z) + BFLO(xB.z), 0.f), w1.x, pB);
        pB = fmaf(fmaxf(BFHI(hsB.z) + BFHI(xB.z), 0.f), w1.y, pB);
        pB = fmaf(fmaxf(BFLO(hsB.w) + BFLO(xB.w), 0.f), w1.z, pB);
        pB = fmaf(fmaxf(BFHI(hsB.w) + BFHI(xB.w), 0.f), w1.w, pB);

#pragma unroll
        for (int off = 32; off > 0; off >>= 1) {
            pA += __shfl_down(pA, off, 64);
            pB += __shfl_down(pB, off, 64);
        }
        if (lane == 0) {
            out[e0]     = 0.5f * pA + bias;
            out[e0 + 1] = 0.5f * pB + bias;
        }
    }
}

// ---------------------------------------------------------------------------
// Inputs: 0:x[N,64] f32  1:edge_index3[2,E] i32  2,3: edge_attr (unused)
//         4: batch (unused)  5:W1[128,256] 6:b1[256] 7:W2[256,1] 8:b2[1]
// Output: [E] f32.  Workspace: N*512 bf16 table (51.2 MB).
// ---------------------------------------------------------------------------
extern "C" void kernel_launch(void* const* d_in, const int* in_sizes, int n_in,
                              void* d_out, int out_size, void* d_ws, size_t ws_size,
                              hipStream_t stream) {
    const float* x  = (const float*)d_in[0];
    const int*   ei = (const int*)d_in[1];
    const float* W1 = (const float*)d_in[5];
    const float* b1 = (const float*)d_in[6];
    const float* W2 = (const float*)d_in[7];
    const float* b2 = (const float*)d_in[8];
    float* out = (float*)d_out;

    const int n  = in_sizes[0] / DIM;  // 50000 nodes
    const int ne = in_sizes[1] / 2;    // 500000 edges

    unsigned short* tab = (unsigned short*)d_ws;   // [n, 512] bf16 [A|B]

    const int rblocks = (n + 63) / 64;
    node_gemm<<<rblocks * 4, 256, 0, stream>>>(x, W1, b1, tab, n);
    edge_mlp<<<4096, 256, 0, stream>>>(ei, tab, W2, b2, out, ne);
}

// Round 3
// 260.120 us; speedup vs baseline: 1.9391x; 1.1057x over previous
//
#include <hip/hip_runtime.h>

#define DIM 64
#define HID 256           // 4*dim
#define ROW 512           // bf16 entries per node row: [A(256)|B(256)]

typedef short s8v __attribute__((ext_vector_type(8)));   // 8 bf16 (4 VGPRs)
typedef float f4v __attribute__((ext_vector_type(4)));   // 4 fp32 acc

union U16 { uint4 u; s8v s; };

__device__ __forceinline__ unsigned short bf16_rne(float f) {
    unsigned u = __float_as_uint(f);
    u = (u + 0x7fffu + ((u >> 16) & 1u)) >> 16;
    return (unsigned short)u;
}
__device__ __forceinline__ unsigned pk_bf16(float a, float b) {
    return (unsigned)bf16_rne(a) | ((unsigned)bf16_rne(b) << 16);
}
#define BFLO(u) __uint_as_float((u) << 16)
#define BFHI(u) __uint_as_float((u) & 0xffff0000u)

// ---------------------------------------------------------------------------
// Kernel 0: swizzle Wcat = [W1[0:64,:] | W1[64:128,:]]  (64 x 512 fp32)
// into bf16 B-fragments for mfma_f32_16x16x32_bf16:
//   frag f = (ct*2 + t)*64 + lane;  value j = Wcat[t*32 + (lane>>4)*8 + j][ct*16 + (lane&15)]
// 32 col-tiles x 2 k-tiles x 64 lanes x 8 bf16 = 64 KB.
// ---------------------------------------------------------------------------
__global__ __launch_bounds__(256) void prep_wfrag(
    const float* __restrict__ W1, unsigned short* __restrict__ wf)
{
    const int f = blockIdx.x * 256 + threadIdx.x;
    if (f >= 32 * 2 * 64) return;
    const int lane = f & 63;
    const int t    = (f >> 6) & 1;
    const int ct   = f >> 7;
    const int col  = ct * 16 + (lane & 15);
    const int k0   = t * 32 + (lane >> 4) * 8;
    const float* __restrict__ wsrc =
        W1 + ((col >= HID) ? (DIM * HID + col - HID) : col);
    unsigned short v[8];
#pragma unroll
    for (int j = 0; j < 8; ++j) v[j] = bf16_rne(wsrc[(size_t)(k0 + j) * HID]);
    uint4 o;
    o.x = (unsigned)v[0] | ((unsigned)v[1] << 16);
    o.y = (unsigned)v[2] | ((unsigned)v[3] << 16);
    o.z = (unsigned)v[4] | ((unsigned)v[5] << 16);
    o.w = (unsigned)v[6] | ((unsigned)v[7] << 16);
    *(uint4*)(wf + (size_t)f * 8) = o;
}

// ---------------------------------------------------------------------------
// Kernel 1: MFMA node GEMM.  tab[n x 512](bf16) = Xbf16[n x 64] @ Wcat + [b1|0]
// Block = 4 waves, no LDS. Wave w: rows blockIdx*32 + (w>>1)*16, col half (w&1).
// Per wave: 2 A-frags (K=64), loop 16 col-tiles: 2 frag loads + 2 MFMA + store.
// ---------------------------------------------------------------------------
__global__ __launch_bounds__(256) void node_mfma(
    const float* __restrict__ x, const unsigned short* __restrict__ wf,
    const float* __restrict__ b1, unsigned short* __restrict__ tab, int n)
{
    const int lane    = threadIdx.x & 63;
    const int w       = threadIdx.x >> 6;
    const int rowgrp  = w >> 1;
    const int colhalf = w & 1;
    const int m       = lane & 15;
    const int quad    = lane >> 4;
    const int rbase   = blockIdx.x * 32 + rowgrp * 16;

    // ---- A-frags: lane holds x[rbase+m][t*32 + quad*8 .. +8) as bf16x8 ----
    const int arow = rbase + m;
    const float* __restrict__ xr = x + (size_t)((arow < n) ? arow : (n - 1)) * DIM;
    s8v a[2];
#pragma unroll
    for (int t = 0; t < 2; ++t) {
        const float4 lo = *(const float4*)(xr + t * 32 + quad * 8);
        const float4 hi = *(const float4*)(xr + t * 32 + quad * 8 + 4);
        U16 u;
        u.u.x = pk_bf16(lo.x, lo.y);
        u.u.y = pk_bf16(lo.z, lo.w);
        u.u.z = pk_bf16(hi.x, hi.y);
        u.u.w = pk_bf16(hi.z, hi.w);
        a[t] = u.s;
    }

    // C rows (per reg) and validity — independent of col-tile
    int grow[4]; bool rok[4];
#pragma unroll
    for (int r = 0; r < 4; ++r) {
        grow[r] = rbase + quad * 4 + r;
        rok[r]  = grow[r] < n;
    }

    const uint4* __restrict__ wfv = (const uint4*)wf;

#pragma unroll 2
    for (int ct = 0; ct < 16; ++ct) {
        const int ctg = colhalf * 16 + ct;       // global col-tile 0..31
        U16 b0u, b1u;
        b0u.u = wfv[(ctg * 2 + 0) * 64 + lane];
        b1u.u = wfv[(ctg * 2 + 1) * 64 + lane];

        f4v acc = {0.f, 0.f, 0.f, 0.f};
        acc = __builtin_amdgcn_mfma_f32_16x16x32_bf16(a[0], b0u.s, acc, 0, 0, 0);
        acc = __builtin_amdgcn_mfma_f32_16x16x32_bf16(a[1], b1u.s, acc, 0, 0, 0);

        const int col = ctg * 16 + m;            // C: col = lane&15
        const float bias = (colhalf == 0) ? b1[col] : 0.0f;
#pragma unroll
        for (int r = 0; r < 4; ++r) {
            if (rok[r])
                tab[(size_t)grow[r] * ROW + col] = bf16_rne(acc[r] + bias);
        }
    }
}

// ---------------------------------------------------------------------------
// Kernel 2: per-edge MLP tail. One wave, FOUR edges per iteration (8 row
// gathers in flight). Node row = 1 KB bf16 [A|B]; lane reads 16 B.
// __shfl_xor(.,32) swaps A/B halves of the d-row so:
//   lanes <32 : relu(A[s]+B[d]).W2chunk ; lanes >=32 : relu(B[s]+A[d]).W2chunk
// Full 64-lane sum = both directions; out = 0.5*sum + b2.
// ---------------------------------------------------------------------------
__global__ __launch_bounds__(256) void edge_mlp(
    const int* __restrict__ ei, const unsigned short* __restrict__ tab,
    const float* __restrict__ W2, const float* __restrict__ b2,
    float* __restrict__ out, int ne)
{
    const int lane = threadIdx.x & 63;
    const int wid  = blockIdx.x * (blockDim.x >> 6) + (threadIdx.x >> 6);
    const int nw   = gridDim.x * (blockDim.x >> 6);
    const int ub   = 8 * (lane & 31);
    const float4 w0 = *(const float4*)(W2 + ub);
    const float4 w1 = *(const float4*)(W2 + ub + 4);
    const float bias = b2[0];

    for (int e0 = wid * 4; e0 < ne; e0 += nw * 4) {
        const int eu = __builtin_amdgcn_readfirstlane(e0);
        uint4 hs[4], hd[4];
#pragma unroll
        for (int q = 0; q < 4; ++q) {
            const int s = ei[eu + q];
            const int d = ei[ne + eu + q];
            hs[q] = ((const uint4*)(tab + (size_t)s * ROW))[lane];
            hd[q] = ((const uint4*)(tab + (size_t)d * ROW))[lane];
        }
        float p[4];
#pragma unroll
        for (int q = 0; q < 4; ++q) {
            uint4 xd;
            xd.x = (unsigned)__shfl_xor((int)hd[q].x, 32, 64);
            xd.y = (unsigned)__shfl_xor((int)hd[q].y, 32, 64);
            xd.z = (unsigned)__shfl_xor((int)hd[q].z, 32, 64);
            xd.w = (unsigned)__shfl_xor((int)hd[q].w, 32, 64);
            float acc = 0.f;
            acc = fmaf(fmaxf(BFLO(hs[q].x) + BFLO(xd.x), 0.f), w0.x, acc);
            acc = fmaf(fmaxf(BFHI(hs[q].x) + BFHI(xd.x), 0.f), w0.y, acc);
            acc = fmaf(fmaxf(BFLO(hs[q].y) + BFLO(xd.y), 0.f), w0.z, acc);
            acc = fmaf(fmaxf(BFHI(hs[q].y) + BFHI(xd.y), 0.f), w0.w, acc);
            acc = fmaf(fmaxf(BFLO(hs[q].z) + BFLO(xd.z), 0.f), w1.x, acc);
            acc = fmaf(fmaxf(BFHI(hs[q].z) + BFHI(xd.z), 0.f), w1.y, acc);
            acc = fmaf(fmaxf(BFLO(hs[q].w) + BFLO(xd.w), 0.f), w1.z, acc);
            acc = fmaf(fmaxf(BFHI(hs[q].w) + BFHI(xd.w), 0.f), w1.w, acc);
            p[q] = acc;
        }
#pragma unroll
        for (int off = 32; off > 0; off >>= 1) {
            p[0] += __shfl_down(p[0], off, 64);
            p[1] += __shfl_down(p[1], off, 64);
            p[2] += __shfl_down(p[2], off, 64);
            p[3] += __shfl_down(p[3], off, 64);
        }
        if (lane == 0) {
            // ne % 4 == 0 and e0 is a multiple of 4 -> full float4 store
            *(float4*)(out + e0) = make_float4(
                0.5f * p[0] + bias, 0.5f * p[1] + bias,
                0.5f * p[2] + bias, 0.5f * p[3] + bias);
        }
    }
}

// ---------------------------------------------------------------------------
// Inputs: 0:x[N,64] f32  1:edge_index3[2,E] i32  2,3: edge_attr (unused)
//         4: batch (unused)  5:W1[128,256] 6:b1[256] 7:W2[256,1] 8:b2[1]
// Output: [E] f32.
// Workspace: tab = N*512 bf16 (51.2 MB), then wf = 64 KB W-fragments.
// ---------------------------------------------------------------------------
extern "C" void kernel_launch(void* const* d_in, const int* in_sizes, int n_in,
                              void* d_out, int out_size, void* d_ws, size_t ws_size,
                              hipStream_t stream) {
    const float* x  = (const float*)d_in[0];
    const int*   ei = (const int*)d_in[1];
    const float* W1 = (const float*)d_in[5];
    const float* b1 = (const float*)d_in[6];
    const float* W2 = (const float*)d_in[7];
    const float* b2 = (const float*)d_in[8];
    float* out = (float*)d_out;

    const int n  = in_sizes[0] / DIM;  // 50000 nodes
    const int ne = in_sizes[1] / 2;    // 500000 edges

    unsigned short* tab = (unsigned short*)d_ws;            // [n,512] bf16
    unsigned short* wf  = tab + (size_t)n * ROW;            // 64 KB frags

    prep_wfrag<<<16, 256, 0, stream>>>(W1, wf);
    node_mfma<<<(n + 31) / 32, 256, 0, stream>>>(x, wf, b1, tab, n);
    edge_mlp<<<4096, 256, 0, stream>>>(ei, tab, W2, b2, out, ne);
}